// Round 3
// baseline (195.123 us; speedup 1.0000x reference)
//
#include <hip/hip_runtime.h>
#include <hip/hip_fp16.h>

#define TOKENS 8192
#define IN_F   4096
#define OUT_F  4096
#define NKT    (IN_F / 128)      // 32 K-tiles of 128 bytes

#define ABYTES 16384             // 128 rows x 128 B
#define BBYTES 32768             // 256 rows x 128 B
#define BUFSZ  (ABYTES + BBYTES) // 49152
typedef __attribute__((ext_vector_type(4))) int i32x4;

// ---------------- prep: pack int32->int8 (x and w) + bias echo ----------------
__global__ void prep_kernel(const int4* __restrict__ xs, const int4* __restrict__ ws,
                            const float* __restrict__ bias,
                            int4* __restrict__ xp, int4* __restrict__ wp,
                            float* __restrict__ out_tail) {
    const int NX = TOKENS * IN_F / 16;
    const int NW = OUT_F * IN_F / 16;
    const int gid = blockIdx.x * blockDim.x + threadIdx.x;
    const int stride = gridDim.x * blockDim.x;
    for (int i = gid; i < NX + NW; i += stride) {
        const int4* s; int4* d; int j;
        if (i < NX) { s = xs; d = xp; j = i; }
        else        { s = ws; d = wp; j = i - NX; }
        int4 a = s[4 * j + 0];
        int4 b = s[4 * j + 1];
        int4 c = s[4 * j + 2];
        int4 e = s[4 * j + 3];
        int4 o;
        o.x = (int)((a.x & 0xffu) | ((a.y & 0xffu) << 8) | ((a.z & 0xffu) << 16) | ((a.w & 0xffu) << 24));
        o.y = (int)((b.x & 0xffu) | ((b.y & 0xffu) << 8) | ((b.z & 0xffu) << 16) | ((b.w & 0xffu) << 24));
        o.z = (int)((c.x & 0xffu) | ((c.y & 0xffu) << 8) | ((c.z & 0xffu) << 16) | ((c.w & 0xffu) << 24));
        o.w = (int)((e.x & 0xffu) | ((e.y & 0xffu) << 8) | ((e.z & 0xffu) << 16) | ((e.w & 0xffu) << 24));
        d[j] = o;
    }
    if (gid < OUT_F) out_tail[gid] = bias[gid];
}

// ---- int8 GEMM: 128x256 tile, BK=128B, 3-buf ring (2-tile lookahead), 2 phases/tile ----
__global__ __launch_bounds__(512, 2) void gemm_i8_kernel(
    const char* __restrict__ A,      // packed x  [TOKENS][IN_F] int8
    const char* __restrict__ B,      // packed w  [OUT_F][IN_F] int8 (B^T layout)
    const float* __restrict__ scale, // [OUT_F]
    const float* __restrict__ bias,  // [OUT_F]
    float* __restrict__ out)         // [TOKENS][OUT_F] fp16-valued fp32
{
    __shared__ char lds[3 * BUFSZ];  // 144 KiB: 3 x {A 16K, B 32K}, 128-B rows

    const int tid  = threadIdx.x;
    const int wid  = tid >> 6;
    const int lane = tid & 63;
    const int wm   = wid >> 2;   // 0..1  (64-row half of the 128 M rows)
    const int wn   = wid & 3;    // 0..3  (64-col quarter of the 256 N cols)

    // XCD-aware bijective swizzle (nwg = 1024, divisible by 8)
    const int nwg = gridDim.x;
    const int bid = blockIdx.x;
    const int swz = (bid & 7) * (nwg >> 3) + (bid >> 3);
    const int tm = swz >> 4;   // 64 M-tiles of 128
    const int tn = swz & 15;   // 16 N-tiles of 256

    const char* ag = A + (size_t)(tm * 128) * IN_F;
    const char* bg = B + (size_t)(tn * 256) * IN_F;

    // Staging: one issue = 512 thr x 16B = 64 rows x 128B. LDS dest LINEAR;
    // global source chunk XOR-swizzled: LDS[row][c] = G[row][c ^ (row&7)].
    const int schunk = ((tid & 7) ^ ((tid >> 3) & 7)) << 4;   // source byte offset in row
    const int srow   = tid >> 3;                              // row within 64-row group
    const int ldst   = tid * 16;                              // linear LDS offset in group

#define STAGE_A(r, t, j)                                                                   \
    __builtin_amdgcn_global_load_lds(                                                      \
        (const __attribute__((address_space(1))) void*)(ag +                               \
            (size_t)((j) * 64 + srow) * IN_F + (t) * 128 + schunk),                        \
        (__attribute__((address_space(3))) void*)(&lds[(r) * BUFSZ + (j) * 8192 + ldst]),  \
        16, 0, 0)

#define STAGE_B(r, t, j)                                                                   \
    __builtin_amdgcn_global_load_lds(                                                      \
        (const __attribute__((address_space(1))) void*)(bg +                               \
            (size_t)((j) * 64 + srow) * IN_F + (t) * 128 + schunk),                        \
        (__attribute__((address_space(3))) void*)(&lds[(r) * BUFSZ + ABYTES +              \
                                                       (j) * 8192 + ldst]),                \
        16, 0, 0)

    // Fragment reads (mfma_i32_16x16x64_i8, layout verified rounds 1-2):
    // lane holds row (lane&15), 16-B k-group kg=lane>>4. Logical chunk = kg | (kk<<2);
    // swizzled chunk = logical ^ (row&7), row&7 == lane&7.
    const int arow  = (wm * 64 + (lane & 15)) * 128;           // + m*2048
    const int brow  = (wn * 64 + (lane & 15)) * 128;           // + n*2048 (B base +ABYTES)
    const int aswz0 = (((lane >> 4) ^ (lane & 7)) << 4);       // kk=0; kk=1 => ^64

    i32x4 acc[4][4];
#pragma unroll
    for (int m = 0; m < 4; ++m)
#pragma unroll
        for (int n = 0; n < 4; ++n)
            acc[m][n] = (i32x4){0, 0, 0, 0};

#define PHASE(r, t, kk, STAGES, TAILSYNC)                                                  \
    do {                                                                                   \
        const char* Lr = &lds[(r) * BUFSZ];                                                \
        const int swk = aswz0 ^ ((kk) << 6);                                               \
        i32x4 afr[4], bfr[4];                                                              \
        _Pragma("unroll")                                                                  \
        for (int m = 0; m < 4; ++m)                                                        \
            afr[m] = *(const i32x4*)(Lr + arow + m * 2048 + swk);                          \
        _Pragma("unroll")                                                                  \
        for (int n = 0; n < 4; ++n)                                                        \
            bfr[n] = *(const i32x4*)(Lr + ABYTES + brow + n * 2048 + swk);                 \
        STAGES;                                                                            \
        __builtin_amdgcn_s_barrier();                                                      \
        asm volatile("s_waitcnt lgkmcnt(0)" ::: "memory");                                 \
        __builtin_amdgcn_sched_barrier(0);                                                 \
        __builtin_amdgcn_s_setprio(1);                                                     \
        _Pragma("unroll")                                                                  \
        for (int m = 0; m < 4; ++m)                                                        \
            _Pragma("unroll")                                                              \
            for (int n = 0; n < 4; ++n)                                                    \
                acc[m][n] = __builtin_amdgcn_mfma_i32_16x16x64_i8(                         \
                    afr[m], bfr[n], acc[m][n], 0, 0, 0);                                   \
        __builtin_amdgcn_s_setprio(0);                                                     \
        TAILSYNC;                                                                          \
        __builtin_amdgcn_s_barrier();                                                      \
        __builtin_amdgcn_sched_barrier(0);                                                 \
    } while (0)

#define VM6 asm volatile("s_waitcnt vmcnt(6)" ::: "memory")
#define VM0 asm volatile("s_waitcnt vmcnt(0)" ::: "memory")

    // Tile t, buffer r=t%3, staging tile t+2 into rs=(t+2)%3 (= buffer read at t-1,
    // freed by t-1's trailing barrier). Boundary vmcnt before trailing barrier of
    // phase 1 waits tile t+1's 6 loads, leaving tile t+2's 6 in flight.
#define TILE_FULL(t, r, rs)                                                                \
    do {                                                                                   \
        PHASE(r, t, 0, { STAGE_A(rs, (t) + 2, 0); STAGE_A(rs, (t) + 2, 1);                 \
                         STAGE_B(rs, (t) + 2, 0); }, );                                    \
        PHASE(r, t, 1, { STAGE_B(rs, (t) + 2, 1); STAGE_B(rs, (t) + 2, 2);                 \
                         STAGE_B(rs, (t) + 2, 3); }, VM6);                                 \
    } while (0)

    // Prologue: stage tiles 0 and 1 (12 loads), wait tile 0 (leave tile 1's 6).
    STAGE_A(0, 0, 0); STAGE_A(0, 0, 1);
    STAGE_B(0, 0, 0); STAGE_B(0, 0, 1); STAGE_B(0, 0, 2); STAGE_B(0, 0, 3);
    STAGE_A(1, 1, 0); STAGE_A(1, 1, 1);
    STAGE_B(1, 1, 0); STAGE_B(1, 1, 1); STAGE_B(1, 1, 2); STAGE_B(1, 1, 3);
    VM6;
    __builtin_amdgcn_s_barrier();
    __builtin_amdgcn_sched_barrier(0);

    for (int tt = 0; tt < 30; tt += 3) {
        TILE_FULL(tt + 0, 0, 2);
        TILE_FULL(tt + 1, 1, 0);
        TILE_FULL(tt + 2, 2, 1);
    }
    // Tail: tile 30 (no stage; trailing wait drains tile 31), tile 31 (no stage).
    PHASE(0, 30, 0, , );
    PHASE(0, 30, 1, , VM0);
    PHASE(1, 31, 0, , );
    PHASE(1, 31, 1, , );

    // ---------------- epilogue: dequant + bias, fp16 round, store fp32 ----------------
    const int col  = tn * 256 + wn * 64 + (lane & 15);
    const int row0 = tm * 128 + wm * 64 + ((lane >> 4) << 2);
    float sc[4], bi[4];
#pragma unroll
    for (int n = 0; n < 4; ++n) {
        sc[n] = scale[col + n * 16];
        bi[n] = bias[col + n * 16];
    }
#pragma unroll
    for (int m = 0; m < 4; ++m)
#pragma unroll
        for (int n = 0; n < 4; ++n)
#pragma unroll
            for (int r = 0; r < 4; ++r) {
                float v = (float)acc[m][n][r] * sc[n] + bi[n];
                out[(size_t)(row0 + m * 16 + r) * OUT_F + col + n * 16] =
                    (float)__float2half_rn(v);
            }
#undef STAGE_A
#undef STAGE_B
#undef PHASE
#undef TILE_FULL
#undef VM6
#undef VM0
}

extern "C" void kernel_launch(void* const* d_in, const int* in_sizes, int n_in,
                              void* d_out, int out_size, void* d_ws, size_t ws_size,
                              hipStream_t stream) {
    const int*   x_i32 = (const int*)d_in[0];
    const int*   w_i32 = (const int*)d_in[1];
    const float* scale = (const float*)d_in[2];
    const float* bias  = (const float*)d_in[3];
    float*       out   = (float*)d_out;

    char* xp = (char*)d_ws;                   // 32 MB packed x
    char* wp = xp + (size_t)TOKENS * IN_F;    // 16 MB packed weight

    prep_kernel<<<3072, 256, 0, stream>>>((const int4*)x_i32, (const int4*)w_i32, bias,
                                          (int4*)xp, (int4*)wp, out + (size_t)TOKENS * OUT_F);

    gemm_i8_kernel<<<(TOKENS / 128) * (OUT_F / 256), 512, 0, stream>>>(xp, wp, scale, bias, out);
}

// Round 4
// 177.008 us; speedup vs baseline: 1.1023x; 1.1023x over previous
//
#include <hip/hip_runtime.h>
#include <hip/hip_fp16.h>

#define TOKENS 8192
#define IN_F   4096
#define OUT_F  4096
#define NKT    (IN_F / 128)      // 32 K-tiles of 128 bytes

#define ABYTES 32768             // A: 256 rows x 128 B
#define BBYTES 32768             // B: 256 rows x 128 B
#define BUFSZ  (ABYTES + BBYTES) // 64 KiB per buffer
typedef __attribute__((ext_vector_type(4))) int i32x4;

// ---------------- prep: pack int32->int8 (x and w) + bias echo ----------------
__global__ void prep_kernel(const int4* __restrict__ xs, const int4* __restrict__ ws,
                            const float* __restrict__ bias,
                            int4* __restrict__ xp, int4* __restrict__ wp,
                            float* __restrict__ out_tail) {
    const int NX = TOKENS * IN_F / 16;
    const int NW = OUT_F * IN_F / 16;
    const int gid = blockIdx.x * blockDim.x + threadIdx.x;
    const int stride = gridDim.x * blockDim.x;
    for (int i = gid; i < NX + NW; i += stride) {
        const int4* s; int4* d; int j;
        if (i < NX) { s = xs; d = xp; j = i; }
        else        { s = ws; d = wp; j = i - NX; }
        int4 a = s[4 * j + 0];
        int4 b = s[4 * j + 1];
        int4 c = s[4 * j + 2];
        int4 e = s[4 * j + 3];
        int4 o;
        o.x = (int)((a.x & 0xffu) | ((a.y & 0xffu) << 8) | ((a.z & 0xffu) << 16) | ((a.w & 0xffu) << 24));
        o.y = (int)((b.x & 0xffu) | ((b.y & 0xffu) << 8) | ((b.z & 0xffu) << 16) | ((b.w & 0xffu) << 24));
        o.z = (int)((c.x & 0xffu) | ((c.y & 0xffu) << 8) | ((c.z & 0xffu) << 16) | ((c.w & 0xffu) << 24));
        o.w = (int)((e.x & 0xffu) | ((e.y & 0xffu) << 8) | ((e.z & 0xffu) << 16) | ((e.w & 0xffu) << 24));
        d[j] = o;
    }
    if (gid < OUT_F) out_tail[gid] = bias[gid];
}

// ---- int8 GEMM: 256x256 tile, BK=128B, 2-buf, 1 barrier/K-tile, intra-wave overlap ----
__global__ __launch_bounds__(512, 2) void gemm_i8_kernel(
    const char* __restrict__ A,      // packed x  [TOKENS][IN_F] int8
    const char* __restrict__ B,      // packed w  [OUT_F][IN_F] int8 (B^T layout)
    const float* __restrict__ scale, // [OUT_F]
    const float* __restrict__ bias,  // [OUT_F]
    float* __restrict__ out)         // [TOKENS][OUT_F] fp16-valued fp32
{
    __shared__ char lds[2 * BUFSZ];  // 128 KiB

    const int tid  = threadIdx.x;
    const int wid  = tid >> 6;
    const int lane = tid & 63;
    const int wm   = wid >> 2;   // 0..1  -> M offset wm*128, 8 frags of 16
    const int wn   = wid & 3;    // 0..3  -> N offset wn*64,  4 frags of 16

    // XCD-aware bijective swizzle (nwg = 512, divisible by 8)
    const int nwg = gridDim.x;
    const int bid = blockIdx.x;
    const int swz = (bid & 7) * (nwg >> 3) + (bid >> 3);
    const int tm = swz >> 4;   // 32 M-tiles of 256
    const int tn = swz & 15;   // 16 N-tiles of 256

    const char* ag = A + (size_t)(tm * 256) * IN_F;
    const char* bg = B + (size_t)(tn * 256) * IN_F;

    // Staging: one issue = 512 thr x 16B = 64 rows x 128B. LDS dest LINEAR;
    // global source chunk XOR-swizzled: LDS[row][c] = G[row][c ^ (row&7)].
    const int schunk = ((tid & 7) ^ ((tid >> 3) & 7)) << 4;
    const int srow   = tid >> 3;
    const int ldst   = tid * 16;

#define STAGE(r, t)                                                                        \
    do {                                                                                   \
        _Pragma("unroll")                                                                  \
        for (int j = 0; j < 4; ++j) {                                                      \
            size_t go = (size_t)(j * 64 + srow) * IN_F + (size_t)(t) * 128 + schunk;       \
            __builtin_amdgcn_global_load_lds(                                              \
                (const __attribute__((address_space(1))) void*)(ag + go),                  \
                (__attribute__((address_space(3))) void*)(&lds[(r) * BUFSZ +               \
                                                              j * 8192 + ldst]),           \
                16, 0, 0);                                                                 \
            __builtin_amdgcn_global_load_lds(                                              \
                (const __attribute__((address_space(1))) void*)(bg + go),                  \
                (__attribute__((address_space(3))) void*)(&lds[(r) * BUFSZ + ABYTES +      \
                                                              j * 8192 + ldst]),           \
                16, 0, 0);                                                                 \
        }                                                                                  \
    } while (0)

    // Fragment reads (mfma_i32_16x16x64_i8, verified): lane holds row lane&15,
    // k-group kg=lane>>4; logical chunk kg|(kk<<2); swizzled = logical ^ (row&7).
    const int arow = (wm * 128 + (lane & 15)) * 128;   // + m*2048
    const int brow = (wn * 64  + (lane & 15)) * 128;   // + n*2048 (B base +ABYTES)
    const int sw0  = ((lane >> 4) ^ (lane & 7)) << 4;  // kk=0; kk=1 => ^0x40

    i32x4 acc[8][4];
#pragma unroll
    for (int m = 0; m < 8; ++m)
#pragma unroll
        for (int n = 0; n < 4; ++n)
            acc[m][n] = (i32x4){0, 0, 0, 0};

    // Prologue: stage tile 0, publish.
    STAGE(0, 0);
    asm volatile("s_waitcnt vmcnt(0)" ::: "memory");
    __builtin_amdgcn_s_barrier();
    __builtin_amdgcn_sched_barrier(0);

#define TILE(t, DOSTAGE)                                                                   \
    do {                                                                                   \
        const char* Lr = &lds[((t) & 1) * BUFSZ];                                          \
        i32x4 af0[8], bf0[4], bf1[4];                                                      \
        _Pragma("unroll")                                                                  \
        for (int m = 0; m < 8; ++m)                                                        \
            af0[m] = *(const i32x4*)(Lr + arow + m * 2048 + sw0);                          \
        _Pragma("unroll")                                                                  \
        for (int n = 0; n < 4; ++n)                                                        \
            bf0[n] = *(const i32x4*)(Lr + ABYTES + brow + n * 2048 + sw0);                 \
        _Pragma("unroll")                                                                  \
        for (int n = 0; n < 4; ++n)                                                        \
            bf1[n] = *(const i32x4*)(Lr + ABYTES + brow + n * 2048 + (sw0 ^ 0x40));        \
        if (DOSTAGE) STAGE(((t) + 1) & 1, (t) + 1);                                        \
        asm volatile("s_waitcnt lgkmcnt(4)" ::: "memory");                                 \
        __builtin_amdgcn_sched_barrier(0);                                                 \
        __builtin_amdgcn_s_setprio(1);                                                     \
        _Pragma("unroll")                                                                  \
        for (int m = 0; m < 8; ++m)                                                        \
            _Pragma("unroll")                                                              \
            for (int n = 0; n < 4; ++n)                                                    \
                acc[m][n] = __builtin_amdgcn_mfma_i32_16x16x64_i8(                         \
                    af0[m], bf0[n], acc[m][n], 0, 0, 0);                                   \
        __builtin_amdgcn_s_setprio(0);                                                     \
        i32x4 af1[8];                                                                      \
        _Pragma("unroll")                                                                  \
        for (int m = 0; m < 8; ++m)                                                        \
            af1[m] = *(const i32x4*)(Lr + arow + m * 2048 + (sw0 ^ 0x40));                 \
        asm volatile("s_waitcnt lgkmcnt(0)" ::: "memory");                                 \
        __builtin_amdgcn_sched_barrier(0);                                                 \
        __builtin_amdgcn_s_setprio(1);                                                     \
        _Pragma("unroll")                                                                  \
        for (int m = 0; m < 8; ++m)                                                        \
            _Pragma("unroll")                                                              \
            for (int n = 0; n < 4; ++n)                                                    \
                acc[m][n] = __builtin_amdgcn_mfma_i32_16x16x64_i8(                         \
                    af1[m], bf1[n], acc[m][n], 0, 0, 0);                                   \
        __builtin_amdgcn_s_setprio(0);                                                     \
        asm volatile("s_waitcnt vmcnt(0)" ::: "memory");                                   \
        __builtin_amdgcn_s_barrier();                                                      \
        __builtin_amdgcn_sched_barrier(0);                                                 \
    } while (0)

    for (int t = 0; t < NKT - 1; ++t) TILE(t, 1);
    TILE(NKT - 1, 0);

    // ---------------- epilogue: dequant + bias, fp16 round, store fp32 ----------------
    const int col  = tn * 256 + wn * 64 + (lane & 15);
    const int row0 = tm * 256 + wm * 128 + ((lane >> 4) << 2);
    float sc[4], bi[4];
#pragma unroll
    for (int n = 0; n < 4; ++n) {
        sc[n] = scale[col + n * 16];
        bi[n] = bias[col + n * 16];
    }
#pragma unroll
    for (int m = 0; m < 8; ++m)
#pragma unroll
        for (int n = 0; n < 4; ++n)
#pragma unroll
            for (int r = 0; r < 4; ++r) {
                float v = (float)acc[m][n][r] * sc[n] + bi[n];
                out[(size_t)(row0 + m * 16 + r) * OUT_F + col + n * 16] =
                    (float)__float2half_rn(v);
            }
#undef STAGE
#undef TILE
}

extern "C" void kernel_launch(void* const* d_in, const int* in_sizes, int n_in,
                              void* d_out, int out_size, void* d_ws, size_t ws_size,
                              hipStream_t stream) {
    const int*   x_i32 = (const int*)d_in[0];
    const int*   w_i32 = (const int*)d_in[1];
    const float* scale = (const float*)d_in[2];
    const float* bias  = (const float*)d_in[3];
    float*       out   = (float*)d_out;

    char* xp = (char*)d_ws;                   // 32 MB packed x
    char* wp = xp + (size_t)TOKENS * IN_F;    // 16 MB packed weight

    prep_kernel<<<3072, 256, 0, stream>>>((const int4*)x_i32, (const int4*)w_i32, bias,
                                          (int4*)xp, (int4*)wp, out + (size_t)TOKENS * OUT_F);

    gemm_i8_kernel<<<(TOKENS / 256) * (OUT_F / 256), 512, 0, stream>>>(xp, wp, scale, bias, out);
}